// Round 9
// baseline (1398.142 us; speedup 1.0000x reference)
//
#include <hip/hip_runtime.h>
#include <cstddef>
#include <cstdint>

// SNN: 4x (Linear + LIF). GEMMs on bf16 MFMA via EXACT 3-term splitting with
// scale-segregated accumulation (same per-acc MFMA chain order as R5-R8 ->
// bit-identical numerics). gemm_v4 (L0/L1/L2): BM256xBN128, BK=64, 8 waves
// (4Mx2N), 3-slot LDS ring (144KB) -> prefetch 2 K-tiles ahead, ONE
// vmcnt(6)+barrier per K-tile, mode-0 3-bit-XOR swizzle (128B rows,
// conflict-free — R8's 64B-row 2-bit layout was the 8.1M-conflict bug).
// L3 keeps the 128-tile gemm_seg. All operands mode-0 pre-swizzled.

#define BETA 0.95f

static constexpr int B_ = 128;
static constexpr int T_ = 64;
static constexpr int M_ = B_ * T_;       // 8192 rows
static constexpr int NOUT = 128;

typedef __bf16 bf16x8 __attribute__((ext_vector_type(8)));
typedef float f32x4 __attribute__((ext_vector_type(4)));
typedef ushort u16x8 __attribute__((ext_vector_type(8)));

__device__ __forceinline__ ushort f32_bf16_rne(float f) {
  uint32_t u = __float_as_uint(f);
  uint32_t r = u + 0x7FFFu + ((u >> 16) & 1u);
  return (ushort)(r >> 16);
}
__device__ __forceinline__ float bf16_f32(ushort h) {
  return __uint_as_float(((uint32_t)h) << 16);
}

// ---------------------------------------------------------------------------
// fp32 -> 3 bf16 exact split, written at mode-0 swizzled slot positions:
// logical (row, k=kb*64+slot*8+i) stored at row*K + kb*64 + (slot^(row&7))*8+i.
// ---------------------------------------------------------------------------
__global__ __launch_bounds__(256) void split3_swz(
    const float* __restrict__ S, ushort* __restrict__ o1,
    ushort* __restrict__ o2, ushort* __restrict__ o3,
    int K, int nslots)
{
  int g = blockIdx.x * 256 + threadIdx.x;
  if (g >= nslots) return;
  int spr = K >> 3;
  int row = g / spr;
  int sl = g - row * spr;
  int kb = sl >> 3;
  int slot = sl & 7;
  int pslot = slot ^ (row & 7);
  const float* src = S + (size_t)row * K + (kb << 6) + (slot << 3);
  size_t dst = (size_t)row * K + (kb << 6) + (pslot << 3);
  u16x8 v1, v2, v3;
#pragma unroll
  for (int i = 0; i < 8; ++i) {
    float f = src[i];
    ushort h1 = f32_bf16_rne(f);
    float r = f - bf16_f32(h1);
    ushort h2 = f32_bf16_rne(r);
    float r2 = r - bf16_f32(h2);
    ushort h3 = f32_bf16_rne(r2);
    v1[i] = h1; v2[i] = h2; v3[i] = h3;
  }
  *reinterpret_cast<u16x8*>(o1 + dst) = v1;
  *reinterpret_cast<u16x8*>(o2 + dst) = v2;
  *reinterpret_cast<u16x8*>(o3 + dst) = v3;
}

// ---------------------------------------------------------------------------
// gemm_seg (kept for L3): 128x128 tile, BK=64, 4 waves, 2-barrier K-step.
// ---------------------------------------------------------------------------
__global__ __launch_bounds__(256) void gemm_seg(
    const ushort* __restrict__ A0, const ushort* __restrict__ A1,
    const ushort* __restrict__ A2,
    const ushort* __restrict__ B0, const ushort* __restrict__ B1,
    const ushort* __restrict__ B2,
    int P, int apack, int bpack, int K, int N, int accum,
    float* __restrict__ C)
{
  __shared__ ushort As[128 * 64];
  __shared__ ushort Bs[128 * 64];

  const int tid = threadIdx.x;
  const int lane = tid & 63;
  const int wid = tid >> 6;
  const int wr = wid >> 1, wc = wid & 1;
  const int lane15 = lane & 15;
  const int lhi = lane >> 4;
  const int rswz = lane15 & 7;
  const int lrow = lane >> 3, lslot = lane & 7;

  int nwg = gridDim.x * gridDim.y;
  int bid = blockIdx.y * gridDim.x + blockIdx.x;
  int cpx = nwg >> 3;
  int sw = (bid & 7) * cpx + (bid >> 3);
  int bx = sw % gridDim.x, by = sw / gridDim.x;
  const int bm = by * 128, bn = bx * 128;

  f32x4 acc[4][4];
#pragma unroll
  for (int i = 0; i < 4; ++i)
#pragma unroll
    for (int j = 0; j < 4; ++j)
      acc[i][j] = (f32x4){0.f, 0.f, 0.f, 0.f};

  const bool isA = (wid < 2);
  ushort* lbase = isA ? As : Bs;
  const int rowbase0 = isA ? bm : bn;
  const int chunk0 = (wid & 1) * 8;

  for (int p = 0; p < P; ++p) {
    int ai = (apack >> (2 * p)) & 3;
    int bi = (bpack >> (2 * p)) & 3;
    const ushort* Ap = ai == 0 ? A0 : (ai == 1 ? A1 : A2);
    const ushort* Bp = bi == 0 ? B0 : (bi == 1 ? B1 : B2);
    const ushort* gsrc = isA ? Ap : Bp;
    for (int k0 = 0; k0 < K; k0 += 64) {
      __syncthreads();
#pragma unroll
      for (int c = 0; c < 8; ++c) {
        int chunk = chunk0 + c;
        int row = chunk * 8 + lrow;
        const ushort* g = gsrc + (size_t)(rowbase0 + row) * K + k0 + (lslot << 3);
        __builtin_amdgcn_global_load_lds(
            (const __attribute__((address_space(1))) void*)(g),
            (__attribute__((address_space(3))) void*)(lbase + chunk * 512),
            16, 0, 0);
      }
      __syncthreads();
#pragma unroll
      for (int kk = 0; kk < 2; ++kk) {
        int sp = ((kk << 2) | lhi) ^ rswz;
        bf16x8 af[4], bg[4];
#pragma unroll
        for (int i = 0; i < 4; ++i)
          af[i] = *(const bf16x8*)(As + (wr * 64 + i * 16 + lane15) * 64 + sp * 8);
#pragma unroll
        for (int j = 0; j < 4; ++j)
          bg[j] = *(const bf16x8*)(Bs + (wc * 64 + j * 16 + lane15) * 64 + sp * 8);
#pragma unroll
        for (int i = 0; i < 4; ++i)
#pragma unroll
          for (int j = 0; j < 4; ++j)
            acc[i][j] = __builtin_amdgcn_mfma_f32_16x16x32_bf16(
                af[i], bg[j], acc[i][j], 0, 0, 0);
      }
    }
  }

#pragma unroll
  for (int j = 0; j < 4; ++j) {
    int col = bn + wc * 64 + j * 16 + lane15;
#pragma unroll
    for (int i = 0; i < 4; ++i) {
      f32x4 v = acc[i][j];
      int r0 = bm + wr * 64 + i * 16 + lhi * 4;
      if (accum) {
#pragma unroll
        for (int r = 0; r < 4; ++r) {
          size_t idx = (size_t)(r0 + r) * N + col;
          C[idx] = C[idx] + v[r];
        }
      } else {
#pragma unroll
        for (int r = 0; r < 4; ++r)
          C[(size_t)(r0 + r) * N + col] = v[r];
      }
    }
  }
}

// ---------------------------------------------------------------------------
// gemm_v4: BM=256, BN=128, BK=64, K=2048, 8 waves (4Mx2N), P chained passes.
// 3-slot LDS ring, slot = 24576 ushorts (A [256][64] then B [128][64]).
// Per K-tile t: read slot t%3 (two k-half sub-phases, 8 ds_read_b128 + 16
// MFMA each), stage tile t+2 into slot (t+2)%3 (6 global_load_lds: 4 A
// interleaved after k0-reads, 2 B after k1-reads), then ONE
// s_waitcnt vmcnt(6) + s_barrier (the 6 newest = t+2 stay in flight; the
// wait confirms t+1, issued one full tile earlier). Mode-0 swizzle:
// sp = ((kk<<2)|lhi) ^ (lane15&7), rows 128 B -> conflict-free.
// Per-acc MFMA chain = (pass, k ascending by 32) -> identical numerics.
// ---------------------------------------------------------------------------
__global__ __launch_bounds__(512) void gemm_v4(
    const ushort* __restrict__ A0, const ushort* __restrict__ A1,
    const ushort* __restrict__ A2,
    const ushort* __restrict__ B0, const ushort* __restrict__ B1,
    const ushort* __restrict__ B2,
    int P, int apack, int bpack, int N, int accum,
    float* __restrict__ C)
{
  __shared__ __align__(16) ushort lds[3 * 24576];  // 144 KB

  const int tid = threadIdx.x;
  const int lane = tid & 63;
  const int wid = tid >> 6;        // 0..7
  const int wm = wid >> 1;         // 0..3  (M quarter, 64 rows)
  const int wn = wid & 1;          // 0..1  (N half, 64 cols)
  const int lane15 = lane & 15;
  const int lhi = lane >> 4;       // 0..3
  const int r7 = lane15 & 7;
  const int sp0 = (lhi ^ r7) * 8;          // k-half 0 granule offset
  const int sp1 = ((4 | lhi) ^ r7) * 8;    // k-half 1 granule offset

  // bijective XCD swizzle (grids are multiples of 8)
  int nwg = gridDim.x * gridDim.y;
  int bid = blockIdx.y * gridDim.x + blockIdx.x;
  int cpx = nwg >> 3;
  int sw = (bid & 7) * cpx + (bid >> 3);
  int bx = sw % gridDim.x, by = sw / gridDim.x;
  const int bm = by * 256, bn = bx * 128;

  // staging coords: granule = 16B; row = l*64 + (tid>>3), gi = tid&7
  const int srow = tid >> 3;       // 0..63
  const int sgi = tid & 7;

  auto segA = [&](int t) -> const ushort* {
    int ai = (apack >> (2 * (t >> 5))) & 3;
    return ai == 0 ? A0 : (ai == 1 ? A1 : A2);
  };
  auto segB = [&](int t) -> const ushort* {
    int bi = (bpack >> (2 * (t >> 5))) & 3;
    return bi == 0 ? B0 : (bi == 1 ? B1 : B2);
  };
  auto stageA = [&](int t, int slot) {   // 4 loads
    const ushort* Ap = segA(t);
    const int k0 = (t & 31) * 64;
    ushort* sb = lds + slot * 24576;
#pragma unroll
    for (int l = 0; l < 4; ++l) {
      int row = l * 64 + srow;
      __builtin_amdgcn_global_load_lds(
          (const __attribute__((address_space(1))) void*)(Ap + (size_t)(bm + row) * 2048 + k0 + sgi * 8),
          (__attribute__((address_space(3))) void*)(sb + row * 64 + sgi * 8), 16, 0, 0);
    }
  };
  auto stageB = [&](int t, int slot) {   // 2 loads
    const ushort* Bp = segB(t);
    const int k0 = (t & 31) * 64;
    ushort* sb = lds + slot * 24576 + 16384;
#pragma unroll
    for (int l = 0; l < 2; ++l) {
      int row = l * 64 + srow;
      __builtin_amdgcn_global_load_lds(
          (const __attribute__((address_space(1))) void*)(Bp + (size_t)(bn + row) * 2048 + k0 + sgi * 8),
          (__attribute__((address_space(3))) void*)(sb + row * 64 + sgi * 8), 16, 0, 0);
    }
  };

  f32x4 acc[4][4];
#pragma unroll
  for (int i = 0; i < 4; ++i)
#pragma unroll
    for (int j = 0; j < 4; ++j)
      acc[i][j] = (f32x4){0.f, 0.f, 0.f, 0.f};

  const int NT = P * 32;

  // prologue: stage tiles 0 and 1 (12 loads); vmcnt(6) -> tile 0 landed
  stageA(0, 0); stageB(0, 0);
  stageA(1, 1); stageB(1, 1);
  asm volatile("s_waitcnt vmcnt(6)" ::: "memory");
  asm volatile("s_barrier" ::: "memory");

  const int abase = (wm * 64 + lane15) * 64;   // + i*1024 + sp
  const int bbase = (wn * 64 + lane15) * 64;   // + j*1024 + sp

  int scur = 0;                 // slot of tile t
  int sdst = 2;                 // slot of tile t+2
  for (int t = 0; t < NT; ++t) {
    const ushort* As = lds + scur * 24576;
    const ushort* Bs = As + 16384;
    int t2 = t + 2;
    if (t2 > NT - 1) t2 = NT - 1;   // clamped dummy keeps ledger uniform

    bf16x8 aa[4], bb[4];
    // ---- k-half 0: 8 ds_reads, stage A(t+2), 16 MFMA ----
#pragma unroll
    for (int i = 0; i < 4; ++i) aa[i] = *(const bf16x8*)(As + abase + i * 1024 + sp0);
#pragma unroll
    for (int j = 0; j < 4; ++j) bb[j] = *(const bf16x8*)(Bs + bbase + j * 1024 + sp0);
    stageA(t2, sdst);
    __builtin_amdgcn_s_setprio(1);
#pragma unroll
    for (int i = 0; i < 4; ++i)
#pragma unroll
      for (int j = 0; j < 4; ++j)
        acc[i][j] = __builtin_amdgcn_mfma_f32_16x16x32_bf16(aa[i], bb[j], acc[i][j], 0, 0, 0);
    __builtin_amdgcn_s_setprio(0);

    // ---- k-half 1: 8 ds_reads, stage B(t+2), 16 MFMA ----
#pragma unroll
    for (int i = 0; i < 4; ++i) aa[i] = *(const bf16x8*)(As + abase + i * 1024 + sp1);
#pragma unroll
    for (int j = 0; j < 4; ++j) bb[j] = *(const bf16x8*)(Bs + bbase + j * 1024 + sp1);
    stageB(t2, sdst);
    __builtin_amdgcn_s_setprio(1);
#pragma unroll
    for (int i = 0; i < 4; ++i)
#pragma unroll
      for (int j = 0; j < 4; ++j)
        acc[i][j] = __builtin_amdgcn_mfma_f32_16x16x32_bf16(aa[i], bb[j], acc[i][j], 0, 0, 0);
    __builtin_amdgcn_s_setprio(0);

    if (t < NT - 1) {
      asm volatile("s_waitcnt vmcnt(6)" ::: "memory");  // tile t+1 landed; t+2 in flight
      asm volatile("s_barrier" ::: "memory");
    }
    scur = (scur == 2) ? 0 : scur + 1;
    sdst = (sdst == 2) ? 0 : sdst + 1;
  }
  asm volatile("s_waitcnt vmcnt(0)" ::: "memory");  // drain clamped dummies

  // epilogue: C/D layout col = lane&15, row = (lane>>4)*4 + reg
#pragma unroll
  for (int i = 0; i < 4; ++i) {
    int r0 = bm + wm * 64 + i * 16 + lhi * 4;
#pragma unroll
    for (int j = 0; j < 4; ++j) {
      int col = bn + wn * 64 + j * 16 + lane15;
      f32x4 v = acc[i][j];
      if (accum) {
#pragma unroll
        for (int r = 0; r < 4; ++r) {
          size_t idx = (size_t)(r0 + r) * N + col;
          C[idx] = C[idx] + v[r];
        }
      } else {
#pragma unroll
        for (int r = 0; r < 4; ++r)
          C[(size_t)(r0 + r) * N + col] = v[r];
      }
    }
  }
}

// ---------------------------------------------------------------------------
// LIF scan: cur = buf[idx] + bias[n] (single rounding). Writes spikes as bf16
// {0,1} in the mode-0 swizzled layout (key = m&7).
// ---------------------------------------------------------------------------
__global__ __launch_bounds__(256) void lif_spk_swz(
    const float* __restrict__ cur, const float* __restrict__ bias,
    ushort* __restrict__ spk, int N, int total)
{
  int g = blockIdx.x * 256 + threadIdx.x;
  if (g >= total) return;
  int b = g / N, n = g - b * N;
  int nb = n >> 6;
  int slot = (n >> 3) & 7;
  int nlow = n & 7;
  float bv = bias[n];
  float mem = 0.f;
  for (int t = 0; t < T_; ++t) {
    int m = b * T_ + t;
    float c = __fadd_rn(cur[(size_t)m * N + n], bv);
    float reset = ((mem - 1.0f) > 0.0f) ? 1.0f : 0.0f;
    mem = __fmul_rn(BETA, mem);
    mem = __fadd_rn(mem, c);
    mem = __fadd_rn(mem, -reset);
    ushort sv = ((mem - 1.0f) > 0.0f) ? (ushort)0x3F80 : (ushort)0;
    spk[(size_t)m * N + (nb << 6) + (((slot ^ (m & 7)) << 3) + nlow)] = sv;
  }
}

__global__ __launch_bounds__(256) void lif_final(
    const float* __restrict__ cur_in, const float* __restrict__ bias,
    float* __restrict__ spk_out, float* __restrict__ mem_out, int N, int total)
{
  int g = blockIdx.x * 256 + threadIdx.x;
  if (g >= total) return;
  int b = g / N, n = g - b * N;
  size_t base = (size_t)b * T_ * N + n;
  float bv = bias[n];
  float mem = 0.f;
  for (int t = 0; t < T_; ++t) {
    size_t idx = base + (size_t)t * N;
    float c = __fadd_rn(cur_in[idx], bv);
    float reset = ((mem - 1.0f) > 0.0f) ? 1.0f : 0.0f;
    mem = __fmul_rn(BETA, mem);
    mem = __fadd_rn(mem, c);
    mem = __fadd_rn(mem, -reset);
    spk_out[idx] = ((mem - 1.0f) > 0.0f) ? 1.0f : 0.0f;
    mem_out[idx] = mem;
  }
}

extern "C" void kernel_launch(void* const* d_in, const int* in_sizes, int n_in,
                              void* d_out, int out_size, void* d_ws, size_t ws_size,
                              hipStream_t stream)
{
  const float* x  = (const float*)d_in[0];
  const float* W0 = (const float*)d_in[1];
  const float* b0 = (const float*)d_in[2];
  const float* W1 = (const float*)d_in[3];
  const float* b1 = (const float*)d_in[4];
  const float* W2 = (const float*)d_in[5];
  const float* b2 = (const float*)d_in[6];
  const float* W3 = (const float*)d_in[7];
  const float* b3 = (const float*)d_in[8];
  float* out = (float*)d_out;

  char* ws = (char*)d_ws;
  size_t off = 0;
  auto take = [&](size_t bytes) -> char* {
    char* p = ws + off;
    off += (bytes + 255) & ~(size_t)255;
    return p;
  };

  ushort* w0s[3], *w1s[3], *w2s[3], *w3s[3], *xs[3];
  for (int i = 0; i < 3; ++i) w0s[i] = (ushort*)take((size_t)2048 * 2048 * 2);
  for (int i = 0; i < 3; ++i) w1s[i] = (ushort*)take((size_t)2048 * 2048 * 2);
  for (int i = 0; i < 3; ++i) w2s[i] = (ushort*)take((size_t)1024 * 2048 * 2);
  for (int i = 0; i < 3; ++i) w3s[i] = (ushort*)take((size_t)128 * 1024 * 2);
  for (int i = 0; i < 3; ++i) xs[i]  = (ushort*)take((size_t)M_ * 2048 * 2);
  float* cur = (float*)take((size_t)M_ * 2048 * 4);
  // spike buffers alias the x-split region (dead after L0 GEMMs)
  ushort* s0 = xs[0];
  ushort* s1 = xs[1];
  ushort* s2 = xs[2];

  dim3 blk(256);

  // --- splits (all mode-0) ---
  {
    int ns = 2048 * 2048 / 8;
    split3_swz<<<(ns + 255) / 256, blk, 0, stream>>>(W0, w0s[0], w0s[1], w0s[2], 2048, ns);
    split3_swz<<<(ns + 255) / 256, blk, 0, stream>>>(W1, w1s[0], w1s[1], w1s[2], 2048, ns);
    ns = 1024 * 2048 / 8;
    split3_swz<<<(ns + 255) / 256, blk, 0, stream>>>(W2, w2s[0], w2s[1], w2s[2], 2048, ns);
    ns = 128 * 1024 / 8;
    split3_swz<<<(ns + 255) / 256, blk, 0, stream>>>(W3, w3s[0], w3s[1], w3s[2], 1024, ns);
    ns = M_ * 2048 / 8;
    split3_swz<<<(ns + 255) / 256, blk, 0, stream>>>(x, xs[0], xs[1], xs[2], 2048, ns);
  }

  // --- L0 (gemm_v4): main x1w1; corr chain x1w2,x2w1,x1w3,x2w2,x3w1 ---
  {
    dim3 grid(2048 / 128, M_ / 256);  // (16, 32) = 512 blocks
    gemm_v4<<<grid, dim3(512), 0, stream>>>(xs[0], xs[1], xs[2], w0s[0], w0s[1], w0s[2],
                                            1, 0, 0, 2048, 0, cur);
    int apack = 0 | (1 << 2) | (0 << 4) | (1 << 6) | (2 << 8);
    int bpack = 1 | (0 << 2) | (2 << 4) | (1 << 6) | (0 << 8);
    gemm_v4<<<grid, dim3(512), 0, stream>>>(xs[0], xs[1], xs[2], w0s[0], w0s[1], w0s[2],
                                            5, apack, bpack, 2048, 1, cur);
    lif_spk_swz<<<(B_ * 2048) / 256, blk, 0, stream>>>(cur, b0, s0, 2048, B_ * 2048);
  }
  // --- L1 (gemm_v4): main s0@w1; corr s0@w2, s0@w3 ---
  {
    dim3 grid(2048 / 128, M_ / 256);
    gemm_v4<<<grid, dim3(512), 0, stream>>>(s0, s0, s0, w1s[0], w1s[1], w1s[2],
                                            1, 0, 0, 2048, 0, cur);
    gemm_v4<<<grid, dim3(512), 0, stream>>>(s0, s0, s0, w1s[0], w1s[1], w1s[2],
                                            2, 0, 1 | (2 << 2), 2048, 1, cur);
    lif_spk_swz<<<(B_ * 2048) / 256, blk, 0, stream>>>(cur, b1, s1, 2048, B_ * 2048);
  }
  // --- L2 (gemm_v4): main s1@w2a; corr s1@w2b, s1@w2c ---
  {
    dim3 grid(1024 / 128, M_ / 256);  // (8, 32) = 256 blocks
    gemm_v4<<<grid, dim3(512), 0, stream>>>(s1, s1, s1, w2s[0], w2s[1], w2s[2],
                                            1, 0, 0, 1024, 0, cur);
    gemm_v4<<<grid, dim3(512), 0, stream>>>(s1, s1, s1, w2s[0], w2s[1], w2s[2],
                                            2, 0, 1 | (2 << 2), 1024, 1, cur);
    lif_spk_swz<<<(B_ * 1024) / 256, blk, 0, stream>>>(cur, b2, s2, 1024, B_ * 1024);
  }
  // --- L3 (gemm_seg) + final LIF ---
  {
    dim3 grid(128 / 128, M_ / 128);
    gemm_seg<<<grid, blk, 0, stream>>>(s2, s2, s2, w3s[0], w3s[1], w3s[2],
                                       1, 0, 0, 1024, 128, 0, cur);
    gemm_seg<<<grid, blk, 0, stream>>>(s2, s2, s2, w3s[0], w3s[1], w3s[2],
                                       2, 0, 1 | (2 << 2), 1024, 128, 1, cur);
    float* spk3 = out;
    float* mem3 = out + (size_t)M_ * NOUT;
    lif_final<<<(B_ * NOUT) / 256, blk, 0, stream>>>(cur, b3, spk3, mem3, NOUT, B_ * NOUT);
  }
}

// Round 10
// 814.809 us; speedup vs baseline: 1.7159x; 1.7159x over previous
//
#include <hip/hip_runtime.h>
#include <cstddef>
#include <cstdint>

// SNN: 4x (Linear + LIF). bf16 MFMA via EXACT 3-term splitting, scale-
// segregated accumulation. gemm_fused<NB,HM>: R6's proven schedule (mode-1
// swizzle, k-half dbuf staging, counted vmcnt, 2 barriers/phase) at
// BM256xBN128 with NB shared-A B-segments per phase (A frags read once,
// reused across segs -> fewer ds_reads/MFMA) and dual accumulators
// (accM = main chain, bit-identical order; accC = corr chain).
// L0 = 3 fused launches grouped by x-seg; L1/L2 = 1 fused launch each;
// L3 = gemm_seg (mode-0). LIF adds bias (single rounding).

#define BETA 0.95f

static constexpr int B_ = 128;
static constexpr int T_ = 64;
static constexpr int M_ = B_ * T_;       // 8192 rows
static constexpr int NOUT = 128;

typedef __bf16 bf16x8 __attribute__((ext_vector_type(8)));
typedef float f32x4 __attribute__((ext_vector_type(4)));
typedef ushort u16x8 __attribute__((ext_vector_type(8)));

__device__ __forceinline__ ushort f32_bf16_rne(float f) {
  uint32_t u = __float_as_uint(f);
  uint32_t r = u + 0x7FFFu + ((u >> 16) & 1u);
  return (ushort)(r >> 16);
}
__device__ __forceinline__ float bf16_f32(ushort h) {
  return __uint_as_float(((uint32_t)h) << 16);
}

// ---------------------------------------------------------------------------
// fp32 -> 3 bf16 exact split at swizzled slot positions.
// mode 0 (gemm_seg): stored slot = slot ^ (row&7)
// mode 1 (gemm_fused): stored slot = (slot&4)|((slot&3)^((row>>1)&3))
// ---------------------------------------------------------------------------
__global__ __launch_bounds__(256) void split3_swz(
    const float* __restrict__ S, ushort* __restrict__ o1,
    ushort* __restrict__ o2, ushort* __restrict__ o3,
    int K, int nslots, int mode)
{
  int g = blockIdx.x * 256 + threadIdx.x;
  if (g >= nslots) return;
  int spr = K >> 3;
  int row = g / spr;
  int sl = g - row * spr;
  int kb = sl >> 3;
  int slot = sl & 7;
  int pslot = mode ? ((slot & 4) | ((slot & 3) ^ ((row >> 1) & 3)))
                   : (slot ^ (row & 7));
  const float* src = S + (size_t)row * K + (kb << 6) + (slot << 3);
  size_t dst = (size_t)row * K + (kb << 6) + (pslot << 3);
  u16x8 v1, v2, v3;
#pragma unroll
  for (int i = 0; i < 8; ++i) {
    float f = src[i];
    ushort h1 = f32_bf16_rne(f);
    float r = f - bf16_f32(h1);
    ushort h2 = f32_bf16_rne(r);
    float r2 = r - bf16_f32(h2);
    ushort h3 = f32_bf16_rne(r2);
    v1[i] = h1; v2[i] = h2; v3[i] = h3;
  }
  *reinterpret_cast<u16x8*>(o1 + dst) = v1;
  *reinterpret_cast<u16x8*>(o2 + dst) = v2;
  *reinterpret_cast<u16x8*>(o3 + dst) = v3;
}

// ---------------------------------------------------------------------------
// gemm_seg (L3 only): 128x128 tile, BK=64, 4 waves, mode-0 swizzle.
// ---------------------------------------------------------------------------
__global__ __launch_bounds__(256) void gemm_seg(
    const ushort* __restrict__ A0, const ushort* __restrict__ A1,
    const ushort* __restrict__ A2,
    const ushort* __restrict__ B0, const ushort* __restrict__ B1,
    const ushort* __restrict__ B2,
    int P, int apack, int bpack, int K, int N, int accum,
    float* __restrict__ C)
{
  __shared__ ushort As[128 * 64];
  __shared__ ushort Bs[128 * 64];

  const int tid = threadIdx.x;
  const int lane = tid & 63;
  const int wid = tid >> 6;
  const int wr = wid >> 1, wc = wid & 1;
  const int lane15 = lane & 15;
  const int lhi = lane >> 4;
  const int rswz = lane15 & 7;
  const int lrow = lane >> 3, lslot = lane & 7;

  int nwg = gridDim.x * gridDim.y;
  int bid = blockIdx.y * gridDim.x + blockIdx.x;
  int cpx = nwg >> 3;
  int sw = (bid & 7) * cpx + (bid >> 3);
  int bx = sw % gridDim.x, by = sw / gridDim.x;
  const int bm = by * 128, bn = bx * 128;

  f32x4 acc[4][4];
#pragma unroll
  for (int i = 0; i < 4; ++i)
#pragma unroll
    for (int j = 0; j < 4; ++j)
      acc[i][j] = (f32x4){0.f, 0.f, 0.f, 0.f};

  const bool isA = (wid < 2);
  ushort* lbase = isA ? As : Bs;
  const int rowbase0 = isA ? bm : bn;
  const int chunk0 = (wid & 1) * 8;

  for (int p = 0; p < P; ++p) {
    int ai = (apack >> (2 * p)) & 3;
    int bi = (bpack >> (2 * p)) & 3;
    const ushort* Ap = ai == 0 ? A0 : (ai == 1 ? A1 : A2);
    const ushort* Bp = bi == 0 ? B0 : (bi == 1 ? B1 : B2);
    const ushort* gsrc = isA ? Ap : Bp;
    for (int k0 = 0; k0 < K; k0 += 64) {
      __syncthreads();
#pragma unroll
      for (int c = 0; c < 8; ++c) {
        int chunk = chunk0 + c;
        int row = chunk * 8 + lrow;
        const ushort* g = gsrc + (size_t)(rowbase0 + row) * K + k0 + (lslot << 3);
        __builtin_amdgcn_global_load_lds(
            (const __attribute__((address_space(1))) void*)(g),
            (__attribute__((address_space(3))) void*)(lbase + chunk * 512),
            16, 0, 0);
      }
      __syncthreads();
#pragma unroll
      for (int kk = 0; kk < 2; ++kk) {
        int sp = ((kk << 2) | lhi) ^ rswz;
        bf16x8 af[4], bg[4];
#pragma unroll
        for (int i = 0; i < 4; ++i)
          af[i] = *(const bf16x8*)(As + (wr * 64 + i * 16 + lane15) * 64 + sp * 8);
#pragma unroll
        for (int j = 0; j < 4; ++j)
          bg[j] = *(const bf16x8*)(Bs + (wc * 64 + j * 16 + lane15) * 64 + sp * 8);
#pragma unroll
        for (int i = 0; i < 4; ++i)
#pragma unroll
          for (int j = 0; j < 4; ++j)
            acc[i][j] = __builtin_amdgcn_mfma_f32_16x16x32_bf16(
                af[i], bg[j], acc[i][j], 0, 0, 0);
      }
    }
  }

#pragma unroll
  for (int j = 0; j < 4; ++j) {
    int col = bn + wc * 64 + j * 16 + lane15;
#pragma unroll
    for (int i = 0; i < 4; ++i) {
      f32x4 v = acc[i][j];
      int r0 = bm + wr * 64 + i * 16 + lhi * 4;
      if (accum) {
#pragma unroll
        for (int r = 0; r < 4; ++r) {
          size_t idx = (size_t)(r0 + r) * N + col;
          C[idx] = C[idx] + v[r];
        }
      } else {
#pragma unroll
        for (int r = 0; r < 4; ++r)
          C[(size_t)(r0 + r) * N + col] = v[r];
      }
    }
  }
}

// ---------------------------------------------------------------------------
// gemm_fused<NB, HM>: BM=256, BN=128, BK=64 (K fixed 2048, NT=32), 8 waves
// (4Mx2N, per-wave 64x64). Per k-half phase: read af[4] once; for each of NB
// B-segs read bf[4] + 16 MFMA (seg0 -> accM if HM else accC; others -> accC).
// Staging clones R6: per phase stage (t+1, same half) into buffer d^1:
// A 2 loads + NB B loads = L = 2+NB; then s_waitcnt vmcnt(L) (drains the
// previous phase's stage = data needed next phase; newest L stay in flight),
// barrier, setprio MFMA, barrier. Mode-1 swizzle (proven conflict-free).
// LDS: A [2][2][256][32] = 64KB; B [2][2][NB][128][32] = NB*32KB.
// Epilogue: HM ? C = accM+accC : C += accC (single rounding each).
// ---------------------------------------------------------------------------
template<int NB, bool HM>
__global__ __launch_bounds__(512) void gemm_fused(
    const ushort* __restrict__ A,
    const ushort* __restrict__ Bs0, const ushort* __restrict__ Bs1,
    const ushort* __restrict__ Bs2,
    int N, float* __restrict__ C)
{
  __shared__ __align__(16) ushort lds[32768 + 2 * 2 * NB * 4096];

  const int tid = threadIdx.x;
  const int lane = tid & 63;
  const int wid = tid >> 6;        // 0..7
  const int wm = wid >> 1;         // 0..3 (64-row M strip)
  const int wn = wid & 1;          // 0..1 (64-col N strip)
  const int lane15 = lane & 15;
  const int lhi = lane >> 4;
  const int s2 = lhi ^ ((lane15 >> 1) & 3);   // mode-1 read granule

  // bijective XCD swizzle (nwg multiple of 8)
  int nwg = gridDim.x * gridDim.y;
  int bid = blockIdx.y * gridDim.x + blockIdx.x;
  int cpx = nwg >> 3;
  int sw = (bid & 7) * cpx + (bid >> 3);
  int bx = sw % gridDim.x, by = sw / gridDim.x;
  const int bm = by * 256, bn = bx * 128;

  const int sr2 = tid >> 2;   // 0..127
  const int sg = tid & 3;     // 16B granule

  auto stage = [&](int t1, int h, int d) {
    const int k0 = t1 * 64 + h * 32;
#pragma unroll
    for (int l = 0; l < 2; ++l) {
      int row = sr2 + l * 128;
      __builtin_amdgcn_global_load_lds(
          (const __attribute__((address_space(1))) void*)(A + (size_t)(bm + row) * 2048 + k0 + sg * 8),
          (__attribute__((address_space(3))) void*)(lds + d * 16384 + h * 8192 + row * 32 + sg * 8),
          16, 0, 0);
    }
#pragma unroll
    for (int s = 0; s < NB; ++s) {
      const ushort* Bp = (s == 0) ? Bs0 : ((s == 1) ? Bs1 : Bs2);
      __builtin_amdgcn_global_load_lds(
          (const __attribute__((address_space(1))) void*)(Bp + (size_t)(bn + sr2) * 2048 + k0 + sg * 8),
          (__attribute__((address_space(3))) void*)(lds + 32768 + ((d * 2 + h) * NB + s) * 4096 + sr2 * 32 + sg * 8),
          16, 0, 0);
    }
  };

  f32x4 accM[4][4], accC[4][4];
#pragma unroll
  for (int i = 0; i < 4; ++i)
#pragma unroll
    for (int j = 0; j < 4; ++j) {
      accM[i][j] = (f32x4){0.f, 0.f, 0.f, 0.f};
      accC[i][j] = (f32x4){0.f, 0.f, 0.f, 0.f};
    }

  // prologue: stage tile 0 halves into buffer 0; confirm half 0
  stage(0, 0, 0);
  stage(0, 1, 0);
  if constexpr (NB == 3) asm volatile("s_waitcnt vmcnt(5)" ::: "memory");
  if constexpr (NB == 2) asm volatile("s_waitcnt vmcnt(4)" ::: "memory");
  if constexpr (NB == 1) asm volatile("s_waitcnt vmcnt(3)" ::: "memory");
  asm volatile("s_barrier" ::: "memory");

  const int NT = 32;
  for (int t = 0; t < NT; ++t) {
    const int d = t & 1;
#pragma unroll
    for (int h = 0; h < 2; ++h) {
      // A frags for this phase (data confirmed at previous phase boundary)
      bf16x8 af[4];
      const ushort* Ab = lds + d * 16384 + h * 8192;
#pragma unroll
      for (int i = 0; i < 4; ++i)
        af[i] = *(const bf16x8*)(Ab + (wm * 64 + i * 16 + lane15) * 32 + s2 * 8);

      if (t < NT - 1) {
        stage(t + 1, h, d ^ 1);
        if constexpr (NB == 3) asm volatile("s_waitcnt vmcnt(5)" ::: "memory");
        if constexpr (NB == 2) asm volatile("s_waitcnt vmcnt(4)" ::: "memory");
        if constexpr (NB == 1) asm volatile("s_waitcnt vmcnt(3)" ::: "memory");
      } else if (h == 0) {
        asm volatile("s_waitcnt vmcnt(0)" ::: "memory");
      }
      asm volatile("s_barrier" ::: "memory");

      __builtin_amdgcn_s_setprio(1);
#pragma unroll
      for (int s = 0; s < NB; ++s) {
        const ushort* Bb = lds + 32768 + ((d * 2 + h) * NB + s) * 4096;
        bf16x8 bf[4];
#pragma unroll
        for (int j = 0; j < 4; ++j)
          bf[j] = *(const bf16x8*)(Bb + (wn * 64 + j * 16 + lane15) * 32 + s2 * 8);
        if (HM && s == 0) {
#pragma unroll
          for (int i = 0; i < 4; ++i)
#pragma unroll
            for (int j = 0; j < 4; ++j)
              accM[i][j] = __builtin_amdgcn_mfma_f32_16x16x32_bf16(af[i], bf[j], accM[i][j], 0, 0, 0);
        } else {
#pragma unroll
          for (int i = 0; i < 4; ++i)
#pragma unroll
            for (int j = 0; j < 4; ++j)
              accC[i][j] = __builtin_amdgcn_mfma_f32_16x16x32_bf16(af[i], bf[j], accC[i][j], 0, 0, 0);
        }
      }
      __builtin_amdgcn_s_setprio(0);
      asm volatile("s_barrier" ::: "memory");
    }
  }

  // epilogue: C/D layout col = lane&15, row = (lane>>4)*4 + reg
#pragma unroll
  for (int i = 0; i < 4; ++i) {
    int r0 = bm + wm * 64 + i * 16 + lhi * 4;
#pragma unroll
    for (int j = 0; j < 4; ++j) {
      int col = bn + wn * 64 + j * 16 + lane15;
      f32x4 vc = accC[i][j];
      if (HM) {
        f32x4 vm = accM[i][j];
#pragma unroll
        for (int r = 0; r < 4; ++r)
          C[(size_t)(r0 + r) * N + col] = vm[r] + vc[r];
      } else {
#pragma unroll
        for (int r = 0; r < 4; ++r) {
          size_t idx = (size_t)(r0 + r) * N + col;
          C[idx] = C[idx] + vc[r];
        }
      }
    }
  }
}

// ---------------------------------------------------------------------------
// LIF scan: cur = buf + bias (single rounding); spikes bf16 {0,1} written in
// swizzled layout (mode selects variant, key = m).
// ---------------------------------------------------------------------------
__global__ __launch_bounds__(256) void lif_spk_swz(
    const float* __restrict__ cur, const float* __restrict__ bias,
    ushort* __restrict__ spk, int N, int total, int mode)
{
  int g = blockIdx.x * 256 + threadIdx.x;
  if (g >= total) return;
  int b = g / N, n = g - b * N;
  int nb = n >> 6;
  int slot = (n >> 3) & 7;
  int nlow = n & 7;
  float bv = bias[n];
  float mem = 0.f;
  for (int t = 0; t < T_; ++t) {
    int m = b * T_ + t;
    float c = __fadd_rn(cur[(size_t)m * N + n], bv);
    float reset = ((mem - 1.0f) > 0.0f) ? 1.0f : 0.0f;
    mem = __fmul_rn(BETA, mem);
    mem = __fadd_rn(mem, c);
    mem = __fadd_rn(mem, -reset);
    ushort sv = ((mem - 1.0f) > 0.0f) ? (ushort)0x3F80 : (ushort)0;
    int ps = mode ? ((slot & 4) | ((slot & 3) ^ ((m >> 1) & 3)))
                  : (slot ^ (m & 7));
    spk[(size_t)m * N + (nb << 6) + (ps << 3) + nlow] = sv;
  }
}

__global__ __launch_bounds__(256) void lif_final(
    const float* __restrict__ cur_in, const float* __restrict__ bias,
    float* __restrict__ spk_out, float* __restrict__ mem_out, int N, int total)
{
  int g = blockIdx.x * 256 + threadIdx.x;
  if (g >= total) return;
  int b = g / N, n = g - b * N;
  size_t base = (size_t)b * T_ * N + n;
  float bv = bias[n];
  float mem = 0.f;
  for (int t = 0; t < T_; ++t) {
    size_t idx = base + (size_t)t * N;
    float c = __fadd_rn(cur_in[idx], bv);
    float reset = ((mem - 1.0f) > 0.0f) ? 1.0f : 0.0f;
    mem = __fmul_rn(BETA, mem);
    mem = __fadd_rn(mem, c);
    mem = __fadd_rn(mem, -reset);
    spk_out[idx] = ((mem - 1.0f) > 0.0f) ? 1.0f : 0.0f;
    mem_out[idx] = mem;
  }
}

extern "C" void kernel_launch(void* const* d_in, const int* in_sizes, int n_in,
                              void* d_out, int out_size, void* d_ws, size_t ws_size,
                              hipStream_t stream)
{
  const float* x  = (const float*)d_in[0];
  const float* W0 = (const float*)d_in[1];
  const float* b0 = (const float*)d_in[2];
  const float* W1 = (const float*)d_in[3];
  const float* b1 = (const float*)d_in[4];
  const float* W2 = (const float*)d_in[5];
  const float* b2 = (const float*)d_in[6];
  const float* W3 = (const float*)d_in[7];
  const float* b3 = (const float*)d_in[8];
  float* out = (float*)d_out;

  char* ws = (char*)d_ws;
  size_t off = 0;
  auto take = [&](size_t bytes) -> char* {
    char* p = ws + off;
    off += (bytes + 255) & ~(size_t)255;
    return p;
  };

  ushort* w0s[3], *w1s[3], *w2s[3], *w3s[3], *xs[3];
  for (int i = 0; i < 3; ++i) w0s[i] = (ushort*)take((size_t)2048 * 2048 * 2);
  for (int i = 0; i < 3; ++i) w1s[i] = (ushort*)take((size_t)2048 * 2048 * 2);
  for (int i = 0; i < 3; ++i) w2s[i] = (ushort*)take((size_t)1024 * 2048 * 2);
  for (int i = 0; i < 3; ++i) w3s[i] = (ushort*)take((size_t)128 * 1024 * 2);
  for (int i = 0; i < 3; ++i) xs[i]  = (ushort*)take((size_t)M_ * 2048 * 2);
  float* cur = (float*)take((size_t)M_ * 2048 * 4);
  // spike buffers alias the x-split region (dead after L0 GEMMs)
  ushort* s0 = xs[0];
  ushort* s1 = xs[1];
  ushort* s2 = xs[2];

  dim3 blk(256);
  dim3 fblk(512);

  // --- splits: mode 1 for fused operands (x, W0, W1, W2); mode 0 for W3 ---
  {
    int ns = 2048 * 2048 / 8;
    split3_swz<<<(ns + 255) / 256, blk, 0, stream>>>(W0, w0s[0], w0s[1], w0s[2], 2048, ns, 1);
    split3_swz<<<(ns + 255) / 256, blk, 0, stream>>>(W1, w1s[0], w1s[1], w1s[2], 2048, ns, 1);
    ns = 1024 * 2048 / 8;
    split3_swz<<<(ns + 255) / 256, blk, 0, stream>>>(W2, w2s[0], w2s[1], w2s[2], 2048, ns, 1);
    ns = 128 * 1024 / 8;
    split3_swz<<<(ns + 255) / 256, blk, 0, stream>>>(W3, w3s[0], w3s[1], w3s[2], 1024, ns, 0);
    ns = M_ * 2048 / 8;
    split3_swz<<<(ns + 255) / 256, blk, 0, stream>>>(x, xs[0], xs[1], xs[2], 2048, ns, 1);
  }

  // --- L0: fused by A-segment ---
  {
    dim3 grid(2048 / 128, M_ / 256);   // (16, 32) = 512 blocks
    gemm_fused<3, true><<<grid, fblk, 0, stream>>>(xs[0], w0s[0], w0s[1], w0s[2], 2048, cur);
    gemm_fused<2, false><<<grid, fblk, 0, stream>>>(xs[1], w0s[0], w0s[1], w0s[1], 2048, cur);
    gemm_fused<1, false><<<grid, fblk, 0, stream>>>(xs[2], w0s[0], w0s[0], w0s[0], 2048, cur);
    lif_spk_swz<<<(B_ * 2048) / 256, blk, 0, stream>>>(cur, b0, s0, 2048, B_ * 2048, 1);
  }
  // --- L1: one fused launch (A = s0 shared by all 3 segs) ---
  {
    dim3 grid(2048 / 128, M_ / 256);
    gemm_fused<3, true><<<grid, fblk, 0, stream>>>(s0, w1s[0], w1s[1], w1s[2], 2048, cur);
    lif_spk_swz<<<(B_ * 2048) / 256, blk, 0, stream>>>(cur, b1, s1, 2048, B_ * 2048, 1);
  }
  // --- L2: one fused launch ---
  {
    dim3 grid(1024 / 128, M_ / 256);   // (8, 32) = 256 blocks
    gemm_fused<3, true><<<grid, fblk, 0, stream>>>(s1, w2s[0], w2s[1], w2s[2], 1024, cur);
    lif_spk_swz<<<(B_ * 1024) / 256, blk, 0, stream>>>(cur, b2, s2, 1024, B_ * 1024, 0);
  }
  // --- L3 (gemm_seg, mode-0) + final LIF ---
  {
    dim3 grid(128 / 128, M_ / 128);
    gemm_seg<<<grid, blk, 0, stream>>>(s2, s2, s2, w3s[0], w3s[1], w3s[2],
                                       1, 0, 0, 1024, 128, 0, cur);
    gemm_seg<<<grid, blk, 0, stream>>>(s2, s2, s2, w3s[0], w3s[1], w3s[2],
                                       2, 0, 1 | (2 << 2), 1024, 128, 1, cur);
    float* spk3 = out;
    float* mem3 = out + (size_t)M_ * NOUT;
    lif_final<<<(B_ * NOUT) / 256, blk, 0, stream>>>(cur, b3, spk3, mem3, NOUT, B_ * NOUT);
  }
}